// Round 7
// baseline (402.047 us; speedup 1.0000x reference)
//
#include <hip/hip_runtime.h>
#include <cstdint>
#include <cstddef>

typedef __bf16 bf16x8 __attribute__((ext_vector_type(8)));
typedef float f32x4 __attribute__((ext_vector_type(4)));
typedef float f32x16 __attribute__((ext_vector_type(16)));

#define SEQ   4096
#define HID   1280
#define NH    16
#define HD    80

__device__ __forceinline__ unsigned short f2bf(float f) {
  unsigned int u = __float_as_uint(f);
  unsigned int r = u + 0x7FFFu + ((u >> 16) & 1u);   // RNE
  return (unsigned short)(r >> 16);
}
__device__ __forceinline__ float bf2f(unsigned short h) {
  return __uint_as_float(((unsigned int)h) << 16);
}
__device__ __forceinline__ __bf16 us2bf(unsigned short u) {
  union { unsigned short s; __bf16 b; } c; c.s = u; return c.b;
}
__device__ __forceinline__ void dma16(const void* g, void* l) {
  __builtin_amdgcn_global_load_lds((const __attribute__((address_space(1))) unsigned int*)g,
                                   (__attribute__((address_space(3))) unsigned int*)l, 16, 0, 0);
}
__device__ __forceinline__ unsigned int cvtpk(float a, float b) {
  unsigned int w;
  asm("v_cvt_pk_bf16_f32 %0, %1, %2" : "=v"(w) : "v"(a), "v"(b));
  return w;
}
__device__ __forceinline__ float lo2f(unsigned int w) { return __uint_as_float(w << 16); }
__device__ __forceinline__ float hi2f(unsigned int w) { return __uint_as_float(w & 0xffff0000u); }

// ---------------- split: f32 -> bf16 hi only ---------------------------------
__global__ __launch_bounds__(256) void split_hi_kernel(const float* __restrict__ x,
                                                       unsigned short* __restrict__ hi,
                                                       int n4) {
  int i = blockIdx.x * 256 + threadIdx.x;
  if (i >= n4) return;
  float4 v = *((const float4*)x + i);
  *((ushort4*)hi + i) = make_ushort4(f2bf(v.x), f2bf(v.y), f2bf(v.z), f2bf(v.w));
}

// ---------------- transpose + split weights (hi/lo) --------------------------
__global__ __launch_bounds__(256) void tsplit_kernel(const float* __restrict__ W,
                                                     unsigned short* __restrict__ Thi,
                                                     unsigned short* __restrict__ Tlo,
                                                     int K, int N) {
  __shared__ float tile[32][33];
  int n0 = blockIdx.x * 32, k0 = blockIdx.y * 32;
  int tx = threadIdx.x & 31, ty = threadIdx.x >> 5;
#pragma unroll
  for (int i = 0; i < 32; i += 8)
    tile[ty + i][tx] = W[(size_t)(k0 + ty + i) * N + n0 + tx];
  __syncthreads();
#pragma unroll
  for (int i = 0; i < 32; i += 8) {
    float v = tile[tx][ty + i];
    size_t idx = (size_t)(n0 + ty + i) * K + (size_t)(k0 + tx);
    unsigned short h = f2bf(v);
    Thi[idx] = h;
    Tlo[idx] = f2bf(v - bf2f(h));
  }
}

// ---------------- 128x128 DMA GEMM, 2-term (A bf16, B hi/lo) -----------------
__global__ __launch_bounds__(256, 3) void gemm128_x2(
    const unsigned short* __restrict__ A, const unsigned short* __restrict__ Bh,
    const unsigned short* __restrict__ Bl, const float* __restrict__ bias,
    float* __restrict__ out0, float* __restrict__ out1, float* __restrict__ out2,
    int M, int N, int K) {
  __shared__ __align__(16) unsigned short sALL[3 * 8192];  // [A | Bh | Bl]

  const int t = threadIdx.x;
  const int lane = t & 63, wave = t >> 6;
  const int c16 = lane & 15, quad = lane >> 4;
  const int bm = blockIdx.y * 128, bn = blockIdx.x * 128;
  const int wr = (wave >> 1) * 64, wc = (wave & 1) * 64;
  const int lrow = lane >> 3;
  const int lswz = (lane & 7) ^ lrow;

  f32x4 acc[4][4];
#pragma unroll
  for (int i = 0; i < 4; ++i)
#pragma unroll
    for (int j = 0; j < 4; ++j) acc[i][j] = (f32x4){0.f, 0.f, 0.f, 0.f};

  const unsigned short* gp[12];
#pragma unroll
  for (int i = 0; i < 12; ++i) {
    const int ua = wave * 12 + i;
    const int arr = ua >> 4, sub = ua & 15;
    const unsigned short* g = (arr == 0) ? A : (arr == 1) ? Bh : Bl;
    const int rowg = ((arr == 0) ? bm : bn) + sub * 8 + lrow;
    gp[i] = g + (size_t)rowg * K + lswz * 8;
  }

  for (int k0 = 0; k0 < K; k0 += 64) {
    __syncthreads();
#pragma unroll
    for (int i = 0; i < 12; ++i)
      dma16(gp[i] + k0, &sALL[(wave * 12 + i) * 512]);
    __syncthreads();
#pragma unroll
    for (int ks = 0; ks < 2; ++ks) {
      bf16x8 a[4], bh[4], bl[4];
#pragma unroll
      for (int mi = 0; mi < 4; ++mi) {
        const int row = wr + mi * 16 + c16;
        const int off = row * 64 + (((ks * 4 + quad) ^ (row & 7)) * 8);
        a[mi] = *(const bf16x8*)&sALL[off];
      }
#pragma unroll
      for (int ni = 0; ni < 4; ++ni) {
        const int row = wc + ni * 16 + c16;
        const int off = row * 64 + (((ks * 4 + quad) ^ (row & 7)) * 8);
        bh[ni] = *(const bf16x8*)&sALL[8192 + off];
        bl[ni] = *(const bf16x8*)&sALL[16384 + off];
      }
#pragma unroll
      for (int mi = 0; mi < 4; ++mi)
#pragma unroll
        for (int ni = 0; ni < 4; ++ni) {
          acc[mi][ni] = __builtin_amdgcn_mfma_f32_16x16x32_bf16(a[mi], bh[ni], acc[mi][ni], 0, 0, 0);
          acc[mi][ni] = __builtin_amdgcn_mfma_f32_16x16x32_bf16(a[mi], bl[ni], acc[mi][ni], 0, 0, 0);
        }
    }
  }
#pragma unroll
  for (int ni = 0; ni < 4; ++ni) {
    int colg = bn + wc + ni * 16 + c16;
    float bv = bias[colg];
    float* op;
    int c = colg;
    if (c < 1280) op = out0;
    else if (c < 2560) { op = out1; c -= 1280; }
    else { op = out2; c -= 2560; }
#pragma unroll
    for (int mi = 0; mi < 4; ++mi)
#pragma unroll
      for (int r = 0; r < 4; ++r) {
        int rowg = bm + wr + mi * 16 + quad * 4 + r;
        op[(size_t)rowg * 1280 + c] = acc[mi][ni][r] + bv;
      }
  }
}

// ---------------- RoPE on q (in place, f32) + k -> packed bf16 hi/lo ---------
__global__ __launch_bounds__(256) void rope_pack_kernel(
    float* __restrict__ qf, const float* __restrict__ kf,
    const float* __restrict__ cs, const float* __restrict__ sn,
    unsigned short* __restrict__ khi, unsigned short* __restrict__ klo) {
  const int h = blockIdx.y;
  const int s = blockIdx.x * 64 + (threadIdx.x >> 2);
  const int p = threadIdx.x & 3;
  float* qrow = qf + (size_t)s * HID + h * HD;
  const float* krow = kf + (size_t)s * HID + h * HD;
  const float* cr = cs + (size_t)s * HD;
  const float* sr = sn + (size_t)s * HD;
  unsigned short* kh = khi + ((size_t)h * SEQ + s) * HD;
  unsigned short* kl = klo + ((size_t)h * SEQ + s) * HD;
#pragma unroll
  for (int j = 0; j < 10; ++j) {
    int d = 10 * p + j;           // 0..39
    float c0 = cr[d], s0 = sr[d], c1 = cr[d + 40], s1 = sr[d + 40];
    float q0 = qrow[d], q1 = qrow[d + 40];
    qrow[d]      = q0 * c0 - q1 * s0;
    qrow[d + 40] = q1 * c1 + q0 * s1;
    float k0 = krow[d], k1 = krow[d + 40];
    float kn0 = k0 * c0 - k1 * s0;
    float kn1 = k1 * c1 + k0 * s1;
    unsigned short h0 = f2bf(kn0), h1 = f2bf(kn1);
    kh[d] = h0;      kl[d] = f2bf(kn0 - bf2f(h0));
    kh[d + 40] = h1; kl[d + 40] = f2bf(kn1 - bf2f(h1));
  }
}

// ---------------- pack V^T: f32 [s][1280] -> bf16 hi/lo [h][80][4096] --------
__global__ __launch_bounds__(256) void vt_pack_kernel(const float* __restrict__ vf,
                                                      unsigned short* __restrict__ vthi,
                                                      unsigned short* __restrict__ vtlo) {
  __shared__ unsigned short sTh[80][72];
  __shared__ unsigned short sTl[80][72];
  const int h = blockIdx.y;
  const int s0 = blockIdx.x * 64;
  const int t = threadIdx.x;
  {
    int row = t >> 2, p = (t & 3) * 20;
    const float* src = vf + (size_t)(s0 + row) * HID + h * HD + p;
#pragma unroll
    for (int i = 0; i < 5; ++i) {
      float4 v = *(const float4*)(src + 4 * i);
      float vv[4] = {v.x, v.y, v.z, v.w};
#pragma unroll
      for (int j = 0; j < 4; ++j) {
        int d = p + 4 * i + j;
        unsigned short hu = f2bf(vv[j]);
        sTh[d][row] = hu;
        sTl[d][row] = f2bf(vv[j] - bf2f(hu));
      }
    }
  }
  __syncthreads();
  if (t < 160) {
    int d = t >> 1, half = (t & 1) * 32;
    size_t base = (size_t)(h * HD + d) * SEQ + s0 + half;
#pragma unroll
    for (int i = 0; i < 8; ++i) {
      *(ushort4*)&vthi[base + 4 * i] = *(ushort4*)&sTh[d][half + 4 * i];
      *(ushort4*)&vtlo[base + 4 * i] = *(ushort4*)&sTl[d][half + 4 * i];
    }
  }
}

// ---------------- scheduler: LPT permutation of 2048 units -------------------
__global__ __launch_bounds__(128) void sched_kernel(const int* __restrict__ cu,
                                                    int* __restrict__ perm,
                                                    unsigned int* __restrict__ ctr) {
  __shared__ int w[128];
  const int t = threadIdx.x;
  if (t == 0) *ctr = 0u;
  int cu_r[9];
#pragma unroll
  for (int i = 0; i < 9; ++i) cu_r[i] = cu[i];
  const int r0 = t * 32;
  int sg0 = 0, sg1 = 0;
#pragma unroll
  for (int i = 1; i < 8; ++i) {
    sg0 += (r0      >= cu_r[i]) ? 1 : 0;
    sg1 += (r0 + 31 >= cu_r[i]) ? 1 : 0;
  }
  const int ck0 = cu_r[sg0] & ~31;
  const int kend = cu_r[sg1 + 1];
  w[t] = (kend - ck0 + 31) >> 5;
  __syncthreads();
  const int wt = w[t];
  int rank = 0;
  for (int i = 0; i < 128; ++i)
    rank += ((w[i] > wt) || (w[i] == wt && i < t)) ? 1 : 0;
#pragma unroll
  for (int hh = 0; hh < 16; ++hh)
    perm[rank * 16 + hh] = hh * 128 + t;
}

// ---------------- attention: wave-autonomous persistent workers --------------
// 768 blocks x 128 thr = 1536 wave-slots pulling 2048 units (LPT order) from a
// global queue. Each wave owns 32 queries + 20KB private LDS staging one 32-key
// chunk (K hi/lo sigma + V^T hi/lo sigma). No __syncthreads: per-wave counted
// s_waitcnt vmcnt only. FIFO discipline:
//   loop top: outstanding K(ci)10+V(ci)10 -> vmcnt(10) drains K(ci)
//   pre-PV:   outstanding V(ci)10+K(ci+1)10 -> vmcnt(10) drains V(ci);
//             LAST chunk has no K(ci+1) -> must be vmcnt(0)  [round-6 bug fix]

#define MFMA32(A, B, C) __builtin_amdgcn_mfma_f32_32x32x16_bf16(A, B, C, 0, 0, 0)

__global__ __launch_bounds__(128, 2) void attn_kernel(
    const float* __restrict__ qf, const unsigned short* __restrict__ khi,
    const unsigned short* __restrict__ klo, const unsigned short* __restrict__ vthi,
    const unsigned short* __restrict__ vtlo, const int* __restrict__ cu,
    unsigned short* __restrict__ ohi, const int* __restrict__ perm,
    unsigned int* __restrict__ ctr) {
  __shared__ __align__(16) unsigned short sAll[20480];   // 40960 B = 2 x 20KB waves

  const int t = threadIdx.x;
  const int lane = t & 63, wave = t >> 6;
  const int ln5 = lane & 31;                    // query col / frag row
  const int hi  = lane >> 5;                    // k-half
  const int ln7 = lane & 7;

  unsigned short* const wb  = sAll + wave * 10240;  // wave-private 20KB
  unsigned short* const sKh = wb;                   // [32 key][80 d] sigma
  unsigned short* const sKl = wb + 2560;
  unsigned short* const sVh = wb + 5120;            // [80 d][32 key] sigma
  unsigned short* const sVl = wb + 7680;

  int cu_r[9];
#pragma unroll
  for (int i = 0; i < 9; ++i) cu_r[i] = cu[i];

  // K DMA source offsets: granule G = i*64+lane -> key=G/10, pos=G%10,
  // src col = pos^(key&7) for pos<8 else pos  (involution)
  int koff[5];
#pragma unroll
  for (int i = 0; i < 5; ++i) {
    const int G = i * 64 + lane;
    const int key = (G * 205) >> 11;            // exact /10 for G<1024
    const int p = G - key * 10;
    const int cl = (p < 8) ? (p ^ (key & 7)) : p;
    koff[i] = key * 80 + cl * 8;
  }
  // V DMA source offsets: granule G = i*64+lane -> d=G>>2, gc=G&3,
  // logical g = gc ^ ((d>>1)&3)  (involution)
  int voff[5];
#pragma unroll
  for (int i = 0; i < 5; ++i) {
    const int G = i * 64 + lane;
    const int d = G >> 2, gc = G & 3;
    const int g = gc ^ ((d >> 1) & 3);
    voff[i] = d * SEQ + g * 8;
  }
  // K read columns (shorts) per kd
  int ccol[5];
#pragma unroll
  for (int c = 0; c < 5; ++c)
    ccol[c] = (c < 4) ? ((((2 * c) + hi) ^ ln7) * 8) : ((8 + hi) * 8);
  // V read column (shorts) per PV step
  int gcol[2];
#pragma unroll
  for (int c = 0; c < 2; ++c)
    gcol[c] = (((2 * c) + hi) ^ ((ln5 >> 1) & 3)) * 8;

  const float qsc = 0.11180339887498949f * 1.4426950408889634f;  // *log2(e)

  for (;;) {
    unsigned int idx = 0;
    if (lane == 0) idx = atomicAdd(ctr, 1u);
    idx = (unsigned int)__shfl((int)idx, 0);
    if (idx >= 2048u) break;
    const int uu = perm[idx];
    const int h = uu >> 7;
    const int r0 = (uu & 127) * 32;

    const int q_my = r0 + ln5;
    int sq = 0, sg0 = 0, sg1 = 0;
#pragma unroll
    for (int i = 1; i < 8; ++i) {
      sq  += (q_my    >= cu_r[i]) ? 1 : 0;
      sg0 += (r0      >= cu_r[i]) ? 1 : 0;
      sg1 += (r0 + 31 >= cu_r[i]) ? 1 : 0;
    }
    const int kb_lo = cu_r[sq], kb_hi = cu_r[sq + 1];
    const int ck0 = cu_r[sg0] & ~31;
    const int kend = cu_r[sg1 + 1];
    const int nchunk = (kend - ck0 + 31) >> 5;

    // Q fragments (B-operand: col=ln5=query, k = kt*16 + hi*8 + j)
    bf16x8 qh[5], ql[5];
    {
      const float* qrow = qf + (size_t)q_my * HID + h * HD;
#pragma unroll
      for (int kt = 0; kt < 5; ++kt) {
        const int d0 = kt * 16 + hi * 8;
        float4 a0 = *(const float4*)(qrow + d0);
        float4 a1 = *(const float4*)(qrow + d0 + 4);
        float va[8] = {a0.x, a0.y, a0.z, a0.w, a1.x, a1.y, a1.z, a1.w};
        bf16x8 hf, lf;
#pragma unroll
        for (int j = 0; j < 8; ++j) {
          float v = va[j] * qsc;
          unsigned short hu = f2bf(v);
          hf[j] = us2bf(hu);
          lf[j] = us2bf(f2bf(v - bf2f(hu)));
        }
        qh[kt] = hf; ql[kt] = lf;
      }
    }

    f32x16 O0, O1, O2;
#pragma unroll
    for (int r = 0; r < 16; ++r) { O0[r] = 0.f; O1[r] = 0.f; O2[r] = 0.f; }
    float m_i = -1e30f, l_i = 0.f;

    const unsigned short* gkh = khi + (size_t)h * SEQ * 80;
    const unsigned short* gkl = klo + (size_t)h * SEQ * 80;
    const unsigned short* gvh = vthi + (size_t)h * HD * SEQ;
    const unsigned short* gvl = vtlo + (size_t)h * HD * SEQ;

    // prologue: stage chunk 0 (K then V; vmcnt FIFO order matters)
    {
      const size_t kb = (size_t)ck0 * 80;
#pragma unroll
      for (int i = 0; i < 5; ++i) dma16(gkh + kb + koff[i], sKh + i * 512);
#pragma unroll
      for (int i = 0; i < 5; ++i) dma16(gkl + kb + koff[i], sKl + i * 512);
#pragma unroll
      for (int i = 0; i < 5; ++i) dma16(gvh + ck0 + voff[i], sVh + i * 512);
#pragma unroll
      for (int i = 0; i < 5; ++i) dma16(gvl + ck0 + voff[i], sVl + i * 512);
    }

    for (int ci = 0; ci < nchunk; ++ci) {
      const int ck = ck0 + ci * 32;
      // wait K of this chunk (V's 10 may remain in flight)
      asm volatile("s_waitcnt vmcnt(10)" ::: "memory");

      // ---- QK: S^T = K.Q^T (15 MFMA) ----
      f32x16 sc;
#pragma unroll
      for (int r = 0; r < 16; ++r) sc[r] = 0.f;
      __builtin_amdgcn_s_setprio(1);
#pragma unroll
      for (int kd = 0; kd < 5; ++kd) {
        const int col = ccol[kd];
        bf16x8 kh = *(const bf16x8*)&sKh[ln5 * 80 + col];
        bf16x8 kl = *(const bf16x8*)&sKl[ln5 * 80 + col];
        sc = MFMA32(kh, qh[kd], sc);
        sc = MFMA32(kh, ql[kd], sc);
        sc = MFMA32(kl, qh[kd], sc);
      }
      __builtin_amdgcn_s_setprio(0);

      // stage K(ci+1): K-buf free after the reads above; hides under SM+PV
      __builtin_amdgcn_sched_barrier(0);
      if (ci + 1 < nchunk) {
        const size_t kb = (size_t)(ck + 32) * 80;
#pragma unroll
        for (int i = 0; i < 5; ++i) dma16(gkh + kb + koff[i], sKh + i * 512);
#pragma unroll
        for (int i = 0; i < 5; ++i) dma16(gkl + kb + koff[i], sKl + i * 512);
      }

      // ---- mask + online softmax (lane-local; key = (r&3)+8*(r>>2)+4*hi) ----
      float mx = -1e30f;
      {
        const int kb = ck + 4 * hi;
#pragma unroll
        for (int r = 0; r < 16; ++r) {
          const int kg = kb + (r & 3) + 8 * (r >> 2);
          float v = (kg >= kb_lo && kg < kb_hi) ? sc[r] : -1e30f;
          sc[r] = v;
          mx = fmaxf(mx, v);
        }
      }
      mx = fmaxf(mx, __shfl_xor(mx, 32));
      const float mnew = fmaxf(m_i, mx);
      const float alpha = exp2f(m_i - mnew);
      float ps = 0.f;
#pragma unroll
      for (int r = 0; r < 16; ++r) {
        const float s = sc[r];
        const float p = (s > -1e29f) ? exp2f(s - mnew) : 0.f;
        ps += p;
        sc[r] = p;
      }
      ps += __shfl_xor(ps, 32);
      l_i = l_i * alpha + ps;
      m_i = mnew;
#pragma unroll
      for (int r = 0; r < 16; ++r) { O0[r] *= alpha; O1[r] *= alpha; O2[r] *= alpha; }

      // wait V of this chunk. Non-last: K(ci+1)'s 10 in flight -> vmcnt(10).
      // LAST chunk: nothing behind V -> vmcnt(10) would be a NO-OP and PV
      // would race the V DMA (round-6 bug). Drain fully instead.
      if (ci + 1 < nchunk) {
        asm volatile("s_waitcnt vmcnt(10)" ::: "memory");
      } else {
        asm volatile("s_waitcnt vmcnt(0)" ::: "memory");
      }

      // ---- PV: O^T += V^T.P (2 steps x 9 MFMA) ----
      __builtin_amdgcn_s_setprio(1);
#pragma unroll
      for (int KT = 0; KT < 2; ++KT) {
        unsigned int A1 = cvtpk(sc[KT * 8 + 0], sc[KT * 8 + 1]);
        unsigned int A2 = cvtpk(sc[KT * 8 + 2], sc[KT * 8 + 3]);
        unsigned int B1 = cvtpk(sc[KT * 8 + 4], sc[KT * 8 + 5]);
        unsigned int B2 = cvtpk(sc[KT * 8 + 6], sc[KT * 8 + 7]);
        float e0 = sc[KT * 8 + 0] - lo2f(A1), e1 = sc[KT * 8 + 1] - hi2f(A1);
        float e2 = sc[KT * 8 + 2] - lo2f(A2), e3 = sc[KT * 8 + 3] - hi2f(A2);
        float e4 = sc[KT * 8 + 4] - lo2f(B1), e5 = sc[KT * 8 + 5] - hi2f(B1);
        float e6 = sc[KT * 8 + 6] - lo2f(B2), e7 = sc[KT * 8 + 7] - hi2f(B2);
        unsigned int C1 = cvtpk(e0, e1), C2 = cvtpk(e2, e3);
        unsigned int D1 = cvtpk(e4, e5), D2 = cvtpk(e6, e7);
        unsigned int T1 = (unsigned int)__shfl_xor((int)(hi ? A1 : B1), 32);
        unsigned int T2 = (unsigned int)__shfl_xor((int)(hi ? A2 : B2), 32);
        unsigned int U1 = (unsigned int)__shfl_xor((int)(hi ? C1 : D1), 32);
        unsigned int U2 = (unsigned int)__shfl_xor((int)(hi ? C2 : D2), 32);
        union { unsigned int w[4]; bf16x8 v; } ph_, pl_;
        ph_.w[0] = hi ? T1 : A1;  ph_.w[1] = hi ? T2 : A2;
        ph_.w[2] = hi ? B1 : T1;  ph_.w[3] = hi ? B2 : T2;
        pl_.w[0] = hi ? U1 : C1;  pl_.w[1] = hi ? U2 : C2;
        pl_.w[2] = hi ? D1 : U1;  pl_.w[3] = hi ? D2 : U2;
        const int vc = gcol[KT];
        bf16x8 vh0 = *(const bf16x8*)&sVh[ln5 * 32 + vc];
        bf16x8 vh1 = *(const bf16x8*)&sVh[(32 + ln5) * 32 + vc];
        bf16x8 vh2 = *(const bf16x8*)&sVh[(64 + (ln5 & 15)) * 32 + vc];
        bf16x8 vl0 = *(const bf16x8*)&sVl[ln5 * 32 + vc];
        bf16x8 vl1 = *(const bf16x8*)&sVl[(32 + ln5) * 32 + vc];
        bf16x8 vl2 = *(const bf16x8*)&sVl[(64 + (ln5 & 15)) * 32 + vc];
        O0 = MFMA32(vh0, ph_.v, O0); O1 = MFMA32(vh1, ph_.v, O1);
        O2 = MFMA32(vh2, ph_.v, O2);
        O0 = MFMA32(vl0, ph_.v, O0); O1 = MFMA32(vl1, ph_.v, O1);
        O2 = MFMA32(vl2, ph_.v, O2);
        O0 = MFMA32(vh0, pl_.v, O0); O1 = MFMA32(vh1, pl_.v, O1);
        O2 = MFMA32(vh2, pl_.v, O2);
      }
      __builtin_amdgcn_s_setprio(0);

      // stage V(ci+1): V-buf free after the reads above; hides under next QK
      __builtin_amdgcn_sched_barrier(0);
      if (ci + 1 < nchunk) {
        const int cn = ck + 32;
#pragma unroll
        for (int i = 0; i < 5; ++i) dma16(gvh + cn + voff[i], sVh + i * 512);
#pragma unroll
        for (int i = 0; i < 5; ++i) dma16(gvl + cn + voff[i], sVl + i * 512);
      }
    }

    // ---- epilogue: normalize + direct stores (C-layout d-quads) ----
    const float inv = 1.0f / l_i;
    unsigned short* orow = ohi + (size_t)q_my * HID + h * HD + 4 * hi;
#pragma unroll
    for (int j = 0; j < 4; ++j) {
      unsigned long long w =
          (unsigned long long)cvtpk(O0[4 * j] * inv, O0[4 * j + 1] * inv) |
          ((unsigned long long)cvtpk(O0[4 * j + 2] * inv, O0[4 * j + 3] * inv) << 32);
      *(unsigned long long*)&orow[8 * j] = w;
    }
#pragma unroll
    for (int j = 0; j < 4; ++j) {
      unsigned long long w =
          (unsigned long long)cvtpk(O1[4 * j] * inv, O1[4 * j + 1] * inv) |
          ((unsigned long long)cvtpk(O1[4 * j + 2] * inv, O1[4 * j + 3] * inv) << 32);
      *(unsigned long long*)&orow[32 + 8 * j] = w;
    }
#pragma unroll
    for (int j = 0; j < 2; ++j) {
      unsigned long long w =
          (unsigned long long)cvtpk(O2[4 * j] * inv, O2[4 * j + 1] * inv) |
          ((unsigned long long)cvtpk(O2[4 * j + 2] * inv, O2[4 * j + 3] * inv) << 32);
      *(unsigned long long*)&orow[64 + 8 * j] = w;
    }
  }
}

// ---------------- host launcher ---------------------------------------------
extern "C" void kernel_launch(void* const* d_in, const int* in_sizes, int n_in,
                              void* d_out, int out_size, void* d_ws, size_t ws_size,
                              hipStream_t stream) {
  const float* x      = (const float*)d_in[0];
  const int*   cu     = (const int*)d_in[1];
  const float* cs     = (const float*)d_in[2];
  const float* sn     = (const float*)d_in[3];
  const float* w_qkv  = (const float*)d_in[4];
  const float* b_qkv  = (const float*)d_in[5];
  const float* w_proj = (const float*)d_in[6];
  const float* b_proj = (const float*)d_in[7];
  float* out = (float*)d_out;

  char* ws = (char*)d_ws;
  float*          qf     = (float*)(ws + 0);
  float*          kf     = (float*)(ws + 20971520ULL);
  unsigned short* vthi   = (unsigned short*)(ws + 20971520ULL);
  unsigned short* vtlo   = (unsigned short*)(ws + 31457280ULL);
  float*          vf     = (float*)(ws + 41943040ULL);
  unsigned short* o_hi   = (unsigned short*)(ws + 41943040ULL);
  unsigned short* x_hi   = (unsigned short*)(ws + 62914560ULL);
  unsigned short* khi    = (unsigned short*)(ws + 62914560ULL);
  unsigned short* klo    = (unsigned short*)(ws + 73400320ULL);
  unsigned short* wqt_hi = (unsigned short*)(ws + 83886080ULL);
  unsigned short* wqt_lo = (unsigned short*)(ws + 93716480ULL);
  unsigned short* wpt_hi = (unsigned short*)(ws + 103546880ULL);
  unsigned short* wpt_lo = (unsigned short*)(ws + 106823680ULL);
  unsigned int*   ctr    = (unsigned int*)(ws + 83886080ULL);        // dead wqt
  int*            perm   = (int*)(ws + 83886080ULL + 64);            // dead wqt

  split_hi_kernel<<<5120, 256, 0, stream>>>(x, x_hi, 1310720);
  tsplit_kernel<<<dim3(120, 40), 256, 0, stream>>>(w_qkv, wqt_hi, wqt_lo, 1280, 3840);
  tsplit_kernel<<<dim3(40, 40), 256, 0, stream>>>(w_proj, wpt_hi, wpt_lo, 1280, 1280);
  gemm128_x2<<<dim3(30, 32), 256, 0, stream>>>(x_hi, wqt_hi, wqt_lo, b_qkv,
                                               qf, kf, vf, 4096, 3840, 1280);
  rope_pack_kernel<<<dim3(64, 16), 256, 0, stream>>>(qf, kf, cs, sn, khi, klo);
  vt_pack_kernel<<<dim3(64, 16), 256, 0, stream>>>(vf, vthi, vtlo);
  sched_kernel<<<1, 128, 0, stream>>>(cu, perm, ctr);
  attn_kernel<<<768, 128, 0, stream>>>(qf, khi, klo, vthi, vtlo, cu, o_hi, perm, ctr);
  gemm128_x2<<<dim3(10, 32), 256, 0, stream>>>(o_hi, wpt_hi, wpt_lo, b_proj,
                                               out, nullptr, nullptr, 4096, 1280, 1280);
}

// Round 8
// 370.579 us; speedup vs baseline: 1.0849x; 1.0849x over previous
//
#include <hip/hip_runtime.h>
#include <cstdint>
#include <cstddef>

typedef __bf16 bf16x8 __attribute__((ext_vector_type(8)));
typedef float f32x4 __attribute__((ext_vector_type(4)));
typedef float f32x16 __attribute__((ext_vector_type(16)));

#define SEQ   4096
#define HID   1280
#define NH    16
#define HD    80

__device__ __forceinline__ unsigned short f2bf(float f) {
  unsigned int u = __float_as_uint(f);
  unsigned int r = u + 0x7FFFu + ((u >> 16) & 1u);   // RNE
  return (unsigned short)(r >> 16);
}
__device__ __forceinline__ float bf2f(unsigned short h) {
  return __uint_as_float(((unsigned int)h) << 16);
}
__device__ __forceinline__ __bf16 us2bf(unsigned short u) {
  union { unsigned short s; __bf16 b; } c; c.s = u; return c.b;
}
__device__ __forceinline__ void dma16(const void* g, void* l) {
  __builtin_amdgcn_global_load_lds((const __attribute__((address_space(1))) unsigned int*)g,
                                   (__attribute__((address_space(3))) unsigned int*)l, 16, 0, 0);
}
__device__ __forceinline__ unsigned int cvtpk(float a, float b) {
  unsigned int w;
  asm("v_cvt_pk_bf16_f32 %0, %1, %2" : "=v"(w) : "v"(a), "v"(b));
  return w;
}
__device__ __forceinline__ float lo2f(unsigned int w) { return __uint_as_float(w << 16); }
__device__ __forceinline__ float hi2f(unsigned int w) { return __uint_as_float(w & 0xffff0000u); }

// ---------------- split: f32 -> bf16 hi only ---------------------------------
__global__ __launch_bounds__(256) void split_hi_kernel(const float* __restrict__ x,
                                                       unsigned short* __restrict__ hi,
                                                       int n4) {
  int i = blockIdx.x * 256 + threadIdx.x;
  if (i >= n4) return;
  float4 v = *((const float4*)x + i);
  *((ushort4*)hi + i) = make_ushort4(f2bf(v.x), f2bf(v.y), f2bf(v.z), f2bf(v.w));
}

// ---------------- transpose + split weights (hi/lo) --------------------------
__global__ __launch_bounds__(256) void tsplit_kernel(const float* __restrict__ W,
                                                     unsigned short* __restrict__ Thi,
                                                     unsigned short* __restrict__ Tlo,
                                                     int K, int N) {
  __shared__ float tile[32][33];
  int n0 = blockIdx.x * 32, k0 = blockIdx.y * 32;
  int tx = threadIdx.x & 31, ty = threadIdx.x >> 5;
#pragma unroll
  for (int i = 0; i < 32; i += 8)
    tile[ty + i][tx] = W[(size_t)(k0 + ty + i) * N + n0 + tx];
  __syncthreads();
#pragma unroll
  for (int i = 0; i < 32; i += 8) {
    float v = tile[tx][ty + i];
    size_t idx = (size_t)(n0 + ty + i) * K + (size_t)(k0 + tx);
    unsigned short h = f2bf(v);
    Thi[idx] = h;
    Tlo[idx] = f2bf(v - bf2f(h));
  }
}

// ---------------- 128x128 DMA GEMM, 2-term (A bf16, B hi/lo) -----------------
__global__ __launch_bounds__(256, 3) void gemm128_x2(
    const unsigned short* __restrict__ A, const unsigned short* __restrict__ Bh,
    const unsigned short* __restrict__ Bl, const float* __restrict__ bias,
    float* __restrict__ out0, float* __restrict__ out1, float* __restrict__ out2,
    int M, int N, int K) {
  __shared__ __align__(16) unsigned short sALL[3 * 8192];  // [A | Bh | Bl]

  const int t = threadIdx.x;
  const int lane = t & 63, wave = t >> 6;
  const int c16 = lane & 15, quad = lane >> 4;
  const int bm = blockIdx.y * 128, bn = blockIdx.x * 128;
  const int wr = (wave >> 1) * 64, wc = (wave & 1) * 64;
  const int lrow = lane >> 3;
  const int lswz = (lane & 7) ^ lrow;

  f32x4 acc[4][4];
#pragma unroll
  for (int i = 0; i < 4; ++i)
#pragma unroll
    for (int j = 0; j < 4; ++j) acc[i][j] = (f32x4){0.f, 0.f, 0.f, 0.f};

  const unsigned short* gp[12];
#pragma unroll
  for (int i = 0; i < 12; ++i) {
    const int ua = wave * 12 + i;
    const int arr = ua >> 4, sub = ua & 15;
    const unsigned short* g = (arr == 0) ? A : (arr == 1) ? Bh : Bl;
    const int rowg = ((arr == 0) ? bm : bn) + sub * 8 + lrow;
    gp[i] = g + (size_t)rowg * K + lswz * 8;
  }

  for (int k0 = 0; k0 < K; k0 += 64) {
    __syncthreads();
#pragma unroll
    for (int i = 0; i < 12; ++i)
      dma16(gp[i] + k0, &sALL[(wave * 12 + i) * 512]);
    __syncthreads();
#pragma unroll
    for (int ks = 0; ks < 2; ++ks) {
      bf16x8 a[4], bh[4], bl[4];
#pragma unroll
      for (int mi = 0; mi < 4; ++mi) {
        const int row = wr + mi * 16 + c16;
        const int off = row * 64 + (((ks * 4 + quad) ^ (row & 7)) * 8);
        a[mi] = *(const bf16x8*)&sALL[off];
      }
#pragma unroll
      for (int ni = 0; ni < 4; ++ni) {
        const int row = wc + ni * 16 + c16;
        const int off = row * 64 + (((ks * 4 + quad) ^ (row & 7)) * 8);
        bh[ni] = *(const bf16x8*)&sALL[8192 + off];
        bl[ni] = *(const bf16x8*)&sALL[16384 + off];
      }
#pragma unroll
      for (int mi = 0; mi < 4; ++mi)
#pragma unroll
        for (int ni = 0; ni < 4; ++ni) {
          acc[mi][ni] = __builtin_amdgcn_mfma_f32_16x16x32_bf16(a[mi], bh[ni], acc[mi][ni], 0, 0, 0);
          acc[mi][ni] = __builtin_amdgcn_mfma_f32_16x16x32_bf16(a[mi], bl[ni], acc[mi][ni], 0, 0, 0);
        }
    }
  }
#pragma unroll
  for (int ni = 0; ni < 4; ++ni) {
    int colg = bn + wc + ni * 16 + c16;
    float bv = bias[colg];
    float* op;
    int c = colg;
    if (c < 1280) op = out0;
    else if (c < 2560) { op = out1; c -= 1280; }
    else { op = out2; c -= 2560; }
#pragma unroll
    for (int mi = 0; mi < 4; ++mi)
#pragma unroll
      for (int r = 0; r < 4; ++r) {
        int rowg = bm + wr + mi * 16 + quad * 4 + r;
        op[(size_t)rowg * 1280 + c] = acc[mi][ni][r] + bv;
      }
  }
}

// ---------------- RoPE on q (in place, f32) + k -> packed bf16 hi/lo ---------
__global__ __launch_bounds__(256) void rope_pack_kernel(
    float* __restrict__ qf, const float* __restrict__ kf,
    const float* __restrict__ cs, const float* __restrict__ sn,
    unsigned short* __restrict__ khi, unsigned short* __restrict__ klo) {
  const int h = blockIdx.y;
  const int s = blockIdx.x * 64 + (threadIdx.x >> 2);
  const int p = threadIdx.x & 3;
  float* qrow = qf + (size_t)s * HID + h * HD;
  const float* krow = kf + (size_t)s * HID + h * HD;
  const float* cr = cs + (size_t)s * HD;
  const float* sr = sn + (size_t)s * HD;
  unsigned short* kh = khi + ((size_t)h * SEQ + s) * HD;
  unsigned short* kl = klo + ((size_t)h * SEQ + s) * HD;
#pragma unroll
  for (int j = 0; j < 10; ++j) {
    int d = 10 * p + j;           // 0..39
    float c0 = cr[d], s0 = sr[d], c1 = cr[d + 40], s1 = sr[d + 40];
    float q0 = qrow[d], q1 = qrow[d + 40];
    qrow[d]      = q0 * c0 - q1 * s0;
    qrow[d + 40] = q1 * c1 + q0 * s1;
    float k0 = krow[d], k1 = krow[d + 40];
    float kn0 = k0 * c0 - k1 * s0;
    float kn1 = k1 * c1 + k0 * s1;
    unsigned short h0 = f2bf(kn0), h1 = f2bf(kn1);
    kh[d] = h0;      kl[d] = f2bf(kn0 - bf2f(h0));
    kh[d + 40] = h1; kl[d + 40] = f2bf(kn1 - bf2f(h1));
  }
}

// ---------------- pack V^T: f32 [s][1280] -> bf16 hi/lo [h][80][4096] --------
__global__ __launch_bounds__(256) void vt_pack_kernel(const float* __restrict__ vf,
                                                      unsigned short* __restrict__ vthi,
                                                      unsigned short* __restrict__ vtlo) {
  __shared__ unsigned short sTh[80][72];
  __shared__ unsigned short sTl[80][72];
  const int h = blockIdx.y;
  const int s0 = blockIdx.x * 64;
  const int t = threadIdx.x;
  {
    int row = t >> 2, p = (t & 3) * 20;
    const float* src = vf + (size_t)(s0 + row) * HID + h * HD + p;
#pragma unroll
    for (int i = 0; i < 5; ++i) {
      float4 v = *(const float4*)(src + 4 * i);
      float vv[4] = {v.x, v.y, v.z, v.w};
#pragma unroll
      for (int j = 0; j < 4; ++j) {
        int d = p + 4 * i + j;
        unsigned short hu = f2bf(vv[j]);
        sTh[d][row] = hu;
        sTl[d][row] = f2bf(vv[j] - bf2f(hu));
      }
    }
  }
  __syncthreads();
  if (t < 160) {
    int d = t >> 1, half = (t & 1) * 32;
    size_t base = (size_t)(h * HD + d) * SEQ + s0 + half;
#pragma unroll
    for (int i = 0; i < 8; ++i) {
      *(ushort4*)&vthi[base + 4 * i] = *(ushort4*)&sTh[d][half + 4 * i];
      *(ushort4*)&vtlo[base + 4 * i] = *(ushort4*)&sTl[d][half + 4 * i];
    }
  }
}

// ---------------- scheduler: 8 per-XCD LPT queues of 256 units ---------------
// Queue x (256 entries at perm[x*256]): heads {2x,2x+1} x 128 tiles in
// descending-weight order, heads interleaved per rank. Tile weights are
// head-independent -> all queues have identical total weight (exact balance).
__global__ __launch_bounds__(128) void sched_kernel(const int* __restrict__ cu,
                                                    int* __restrict__ perm,
                                                    unsigned int* __restrict__ ctr) {
  __shared__ int w[128];
  const int t = threadIdx.x;
  if (t < 8) ctr[t * 16] = 0u;   // 8 counters, 64B apart
  int cu_r[9];
#pragma unroll
  for (int i = 0; i < 9; ++i) cu_r[i] = cu[i];
  const int r0 = t * 32;
  int sg0 = 0, sg1 = 0;
#pragma unroll
  for (int i = 1; i < 8; ++i) {
    sg0 += (r0      >= cu_r[i]) ? 1 : 0;
    sg1 += (r0 + 31 >= cu_r[i]) ? 1 : 0;
  }
  const int ck0 = cu_r[sg0] & ~31;
  const int kend = cu_r[sg1 + 1];
  w[t] = (kend - ck0 + 31) >> 5;
  __syncthreads();
  const int wt = w[t];
  int rank = 0;
  for (int i = 0; i < 128; ++i)
    rank += ((w[i] > wt) || (w[i] == wt && i < t)) ? 1 : 0;
#pragma unroll
  for (int x = 0; x < 8; ++x) {
    perm[x * 256 + rank * 2 + 0] = (2 * x) * 128 + t;
    perm[x * 256 + rank * 2 + 1] = (2 * x + 1) * 128 + t;
  }
}

// ---------------- attention: wave-autonomous workers, XCD-local queues -------
// 768 blocks x 128 thr. Block b pulls from queue b&7 (its XCD under
// round-robin dispatch) -> each XCD touches only 2 heads' K/V (5.2MB, mostly
// L2-resident). Correctness is mapping-independent: any block with residue x
// drains queue x. 96 blocks (192 wave slots) per queue of 256 units -> LPT
// refill. Per-wave structure identical to round 7 (verified): 32 queries/wave,
// 20KB private LDS, counted vmcnt pipeline, vmcnt(0) on final chunk.

#define MFMA32(A, B, C) __builtin_amdgcn_mfma_f32_32x32x16_bf16(A, B, C, 0, 0, 0)

__global__ __launch_bounds__(128, 2) void attn_kernel(
    const float* __restrict__ qf, const unsigned short* __restrict__ khi,
    const unsigned short* __restrict__ klo, const unsigned short* __restrict__ vthi,
    const unsigned short* __restrict__ vtlo, const int* __restrict__ cu,
    unsigned short* __restrict__ ohi, const int* __restrict__ perm,
    unsigned int* __restrict__ ctr) {
  __shared__ __align__(16) unsigned short sAll[20480];   // 40960 B = 2 x 20KB waves

  const int t = threadIdx.x;
  const int lane = t & 63, wave = t >> 6;
  const int ln5 = lane & 31;                    // query col / frag row
  const int hi  = lane >> 5;                    // k-half
  const int ln7 = lane & 7;
  const int xcd = blockIdx.x & 7;

  unsigned short* const wb  = sAll + wave * 10240;  // wave-private 20KB
  unsigned short* const sKh = wb;                   // [32 key][80 d] sigma
  unsigned short* const sKl = wb + 2560;
  unsigned short* const sVh = wb + 5120;            // [80 d][32 key] sigma
  unsigned short* const sVl = wb + 7680;

  int cu_r[9];
#pragma unroll
  for (int i = 0; i < 9; ++i) cu_r[i] = cu[i];

  // K DMA source offsets: granule G = i*64+lane -> key=G/10, pos=G%10,
  // src col = pos^(key&7) for pos<8 else pos  (involution)
  int koff[5];
#pragma unroll
  for (int i = 0; i < 5; ++i) {
    const int G = i * 64 + lane;
    const int key = (G * 205) >> 11;            // exact /10 for G<1024
    const int p = G - key * 10;
    const int cl = (p < 8) ? (p ^ (key & 7)) : p;
    koff[i] = key * 80 + cl * 8;
  }
  // V DMA source offsets: granule G = i*64+lane -> d=G>>2, gc=G&3,
  // logical g = gc ^ ((d>>1)&3)  (involution)
  int voff[5];
#pragma unroll
  for (int i = 0; i < 5; ++i) {
    const int G = i * 64 + lane;
    const int d = G >> 2, gc = G & 3;
    const int g = gc ^ ((d >> 1) & 3);
    voff[i] = d * SEQ + g * 8;
  }
  // K read columns (shorts) per kd
  int ccol[5];
#pragma unroll
  for (int c = 0; c < 5; ++c)
    ccol[c] = (c < 4) ? ((((2 * c) + hi) ^ ln7) * 8) : ((8 + hi) * 8);
  // V read column (shorts) per PV step
  int gcol[2];
#pragma unroll
  for (int c = 0; c < 2; ++c)
    gcol[c] = (((2 * c) + hi) ^ ((ln5 >> 1) & 3)) * 8;

  const float qsc = 0.11180339887498949f * 1.4426950408889634f;  // *log2(e)

  for (;;) {
    unsigned int idx = 0;
    if (lane == 0) idx = atomicAdd(&ctr[xcd * 16], 1u);
    idx = (unsigned int)__shfl((int)idx, 0);
    if (idx >= 256u) break;
    const int uu = perm[xcd * 256 + idx];
    const int h = uu >> 7;
    const int r0 = (uu & 127) * 32;

    const int q_my = r0 + ln5;
    int sq = 0, sg0 = 0, sg1 = 0;
#pragma unroll
    for (int i = 1; i < 8; ++i) {
      sq  += (q_my    >= cu_r[i]) ? 1 : 0;
      sg0 += (r0      >= cu_r[i]) ? 1 : 0;
      sg1 += (r0 + 31 >= cu_r[i]) ? 1 : 0;
    }
    const int kb_lo = cu_r[sq], kb_hi = cu_r[sq + 1];
    const int ck0 = cu_r[sg0] & ~31;
    const int kend = cu_r[sg1 + 1];
    const int nchunk = (kend - ck0 + 31) >> 5;

    // Q fragments (B-operand: col=ln5=query, k = kt*16 + hi*8 + j)
    bf16x8 qh[5], ql[5];
    {
      const float* qrow = qf + (size_t)q_my * HID + h * HD;
#pragma unroll
      for (int kt = 0; kt < 5; ++kt) {
        const int d0 = kt * 16 + hi * 8;
        float4 a0 = *(const float4*)(qrow + d0);
        float4 a1 = *(const float4*)(qrow + d0 + 4);
        float va[8] = {a0.x, a0.y, a0.z, a0.w, a1.x, a1.y, a1.z, a1.w};
        bf16x8 hf, lf;
#pragma unroll
        for (int j = 0; j < 8; ++j) {
          float v = va[j] * qsc;
          unsigned short hu = f2bf(v);
          hf[j] = us2bf(hu);
          lf[j] = us2bf(f2bf(v - bf2f(hu)));
        }
        qh[kt] = hf; ql[kt] = lf;
      }
    }

    f32x16 O0, O1, O2;
#pragma unroll
    for (int r = 0; r < 16; ++r) { O0[r] = 0.f; O1[r] = 0.f; O2[r] = 0.f; }
    float m_i = -1e30f, l_i = 0.f;

    const unsigned short* gkh = khi + (size_t)h * SEQ * 80;
    const unsigned short* gkl = klo + (size_t)h * SEQ * 80;
    const unsigned short* gvh = vthi + (size_t)h * HD * SEQ;
    const unsigned short* gvl = vtlo + (size_t)h * HD * SEQ;

    // prologue: stage chunk 0 (K then V; vmcnt FIFO order matters)
    {
      const size_t kb = (size_t)ck0 * 80;
#pragma unroll
      for (int i = 0; i < 5; ++i) dma16(gkh + kb + koff[i], sKh + i * 512);
#pragma unroll
      for (int i = 0; i < 5; ++i) dma16(gkl + kb + koff[i], sKl + i * 512);
#pragma unroll
      for (int i = 0; i < 5; ++i) dma16(gvh + ck0 + voff[i], sVh + i * 512);
#pragma unroll
      for (int i = 0; i < 5; ++i) dma16(gvl + ck0 + voff[i], sVl + i * 512);
    }

    for (int ci = 0; ci < nchunk; ++ci) {
      const int ck = ck0 + ci * 32;
      // wait K of this chunk (V's 10 may remain in flight)
      asm volatile("s_waitcnt vmcnt(10)" ::: "memory");

      // ---- QK: S^T = K.Q^T (15 MFMA) ----
      f32x16 sc;
#pragma unroll
      for (int r = 0; r < 16; ++r) sc[r] = 0.f;
      __builtin_amdgcn_s_setprio(1);
#pragma unroll
      for (int kd = 0; kd < 5; ++kd) {
        const int col = ccol[kd];
        bf16x8 kh = *(const bf16x8*)&sKh[ln5 * 80 + col];
        bf16x8 kl = *(const bf16x8*)&sKl[ln5 * 80 + col];
        sc = MFMA32(kh, qh[kd], sc);
        sc = MFMA32(kh, ql[kd], sc);
        sc = MFMA32(kl, qh[kd], sc);
      }
      __builtin_amdgcn_s_setprio(0);

      // stage K(ci+1): K-buf free after the reads above; hides under SM+PV
      __builtin_amdgcn_sched_barrier(0);
      if (ci + 1 < nchunk) {
        const size_t kb = (size_t)(ck + 32) * 80;
#pragma unroll
        for (int i = 0; i < 5; ++i) dma16(gkh + kb + koff[i], sKh + i * 512);
#pragma unroll
        for (int i = 0; i < 5; ++i) dma16(gkl + kb + koff[i], sKl + i * 512);
      }

      // ---- mask + online softmax (lane-local; key = (r&3)+8*(r>>2)+4*hi) ----
      float mx = -1e30f;
      {
        const int kb = ck + 4 * hi;
#pragma unroll
        for (int r = 0; r < 16; ++r) {
          const int kg = kb + (r & 3) + 8 * (r >> 2);
          float v = (kg >= kb_lo && kg < kb_hi) ? sc[r] : -1e30f;
          sc[r] = v;
          mx = fmaxf(mx, v);
        }
      }
      mx = fmaxf(mx, __shfl_xor(mx, 32));
      const float mnew = fmaxf(m_i, mx);
      const float alpha = exp2f(m_i - mnew);
      float ps = 0.f;
#pragma unroll
      for (int r = 0; r < 16; ++r) {
        const float s = sc[r];
        const float p = (s > -1e29f) ? exp2f(s - mnew) : 0.f;
        ps += p;
        sc[r] = p;
      }
      ps += __shfl_xor(ps, 32);
      l_i = l_i * alpha + ps;
      m_i = mnew;
#pragma unroll
      for (int r = 0; r < 16; ++r) { O0[r] *= alpha; O1[r] *= alpha; O2[r] *= alpha; }

      // wait V of this chunk. Non-last: K(ci+1)'s 10 in flight -> vmcnt(10).
      // LAST chunk: nothing behind V -> must drain fully (round-6 bug fix).
      if (ci + 1 < nchunk) {
        asm volatile("s_waitcnt vmcnt(10)" ::: "memory");
      } else {
        asm volatile("s_waitcnt vmcnt(0)" ::: "memory");
      }

      // ---- PV: O^T += V^T.P (2 steps x 9 MFMA) ----
      __builtin_amdgcn_s_setprio(1);
#pragma unroll
      for (int KT = 0; KT < 2; ++KT) {
        unsigned int A1 = cvtpk(sc[KT * 8 + 0], sc[KT * 8 + 1]);
        unsigned int A2 = cvtpk(sc[KT * 8 + 2], sc[KT * 8 + 3]);
        unsigned int B1 = cvtpk(sc[KT * 8 + 4], sc[KT * 8 + 5]);
        unsigned int B2 = cvtpk(sc[KT * 8 + 6], sc[KT * 8 + 7]);
        float e0 = sc[KT * 8 + 0] - lo2f(A1), e1 = sc[KT * 8 + 1] - hi2f(A1);
        float e2 = sc[KT * 8 + 2] - lo2f(A2), e3 = sc[KT * 8 + 3] - hi2f(A2);
        float e4 = sc[KT * 8 + 4] - lo2f(B1), e5 = sc[KT * 8 + 5] - hi2f(B1);
        float e6 = sc[KT * 8 + 6] - lo2f(B2), e7 = sc[KT * 8 + 7] - hi2f(B2);
        unsigned int C1 = cvtpk(e0, e1), C2 = cvtpk(e2, e3);
        unsigned int D1 = cvtpk(e4, e5), D2 = cvtpk(e6, e7);
        unsigned int T1 = (unsigned int)__shfl_xor((int)(hi ? A1 : B1), 32);
        unsigned int T2 = (unsigned int)__shfl_xor((int)(hi ? A2 : B2), 32);
        unsigned int U1 = (unsigned int)__shfl_xor((int)(hi ? C1 : D1), 32);
        unsigned int U2 = (unsigned int)__shfl_xor((int)(hi ? C2 : D2), 32);
        union { unsigned int w[4]; bf16x8 v; } ph_, pl_;
        ph_.w[0] = hi ? T1 : A1;  ph_.w[1] = hi ? T2 : A2;
        ph_.w[2] = hi ? B1 : T1;  ph_.w[3] = hi ? B2 : T2;
        pl_.w[0] = hi ? U1 : C1;  pl_.w[1] = hi ? U2 : C2;
        pl_.w[2] = hi ? D1 : U1;  pl_.w[3] = hi ? D2 : U2;
        const int vc = gcol[KT];
        bf16x8 vh0 = *(const bf16x8*)&sVh[ln5 * 32 + vc];
        bf16x8 vh1 = *(const bf16x8*)&sVh[(32 + ln5) * 32 + vc];
        bf16x8 vh2 = *(const bf16x8*)&sVh[(64 + (ln5 & 15)) * 32 + vc];
        bf16x8 vl0 = *(const bf16x8*)&sVl[ln5 * 32 + vc];
        bf16x8 vl1 = *(const bf16x8*)&sVl[(32 + ln5) * 32 + vc];
        bf16x8 vl2 = *(const bf16x8*)&sVl[(64 + (ln5 & 15)) * 32 + vc];
        O0 = MFMA32(vh0, ph_.v, O0); O1 = MFMA32(vh1, ph_.v, O1);
        O2 = MFMA32(vh2, ph_.v, O2);
        O0 = MFMA32(vl0, ph_.v, O0); O1 = MFMA32(vl1, ph_.v, O1);
        O2 = MFMA32(vl2, ph_.v, O2);
        O0 = MFMA32(vh0, pl_.v, O0); O1 = MFMA32(vh1, pl_.v, O1);
        O2 = MFMA32(vh2, pl_.v, O2);
      }
      __builtin_amdgcn_s_setprio(0);

      // stage V(ci+1): V-buf free after the reads above; hides under next QK
      __builtin_amdgcn_sched_barrier(0);
      if (ci + 1 < nchunk) {
        const int cn = ck + 32;
#pragma unroll
        for (int i = 0; i < 5; ++i) dma16(gvh + cn + voff[i], sVh + i * 512);
#pragma unroll
        for (int i = 0; i < 5; ++i) dma16(gvl + cn + voff[i], sVl + i * 512);
      }
    }

    // ---- epilogue: normalize + direct stores (C-layout d-quads) ----
    const float inv = 1.0f / l_i;
    unsigned short* orow = ohi + (size_t)q_my * HID + h * HD + 4 * hi;
#pragma unroll
    for (int j = 0; j < 4; ++j) {
      unsigned long long w =
          (unsigned long long)cvtpk(O0[4 * j] * inv, O0[4 * j + 1] * inv) |
          ((unsigned long long)cvtpk(O0[4 * j + 2] * inv, O0[4 * j + 3] * inv) << 32);
      *(unsigned long long*)&orow[8 * j] = w;
    }
#pragma unroll
    for (int j = 0; j < 4; ++j) {
      unsigned long long w =
          (unsigned long long)cvtpk(O1[4 * j] * inv, O1[4 * j + 1] * inv) |
          ((unsigned long long)cvtpk(O1[4 * j + 2] * inv, O1[4 * j + 3] * inv) << 32);
      *(unsigned long long*)&orow[32 + 8 * j] = w;
    }
#pragma unroll
    for (int j = 0; j < 2; ++j) {
      unsigned long long w =
          (unsigned long long)cvtpk(O2[4 * j] * inv, O2[4 * j + 1] * inv) |
          ((unsigned long long)cvtpk(O2[4 * j + 2] * inv, O2[4 * j + 3] * inv) << 32);
      *(unsigned long long*)&orow[64 + 8 * j] = w;
    }
  }
}

// ---------------- host launcher ---------------------------------------------
extern "C" void kernel_launch(void* const* d_in, const int* in_sizes, int n_in,
                              void* d_out, int out_size, void* d_ws, size_t ws_size,
                              hipStream_t stream) {
  const float* x      = (const float*)d_in[0];
  const int*   cu     = (const int*)d_in[1];
  const float* cs     = (const float*)d_in[2];
  const float* sn     = (const float*)d_in[3];
  const float* w_qkv  = (const float*)d_in[4];
  const float* b_qkv  = (const float*)d_in[5];
  const float* w_proj = (const float*)d_in[6];
  const float* b_proj = (const float*)d_in[7];
  float* out = (float*)d_out;

  char* ws = (char*)d_ws;
  float*          qf     = (float*)(ws + 0);
  float*          kf     = (float*)(ws + 20971520ULL);
  unsigned short* vthi   = (unsigned short*)(ws + 20971520ULL);
  unsigned short* vtlo   = (unsigned short*)(ws + 31457280ULL);
  float*          vf     = (float*)(ws + 41943040ULL);
  unsigned short* o_hi   = (unsigned short*)(ws + 41943040ULL);
  unsigned short* x_hi   = (unsigned short*)(ws + 62914560ULL);
  unsigned short* khi    = (unsigned short*)(ws + 62914560ULL);
  unsigned short* klo    = (unsigned short*)(ws + 73400320ULL);
  unsigned short* wqt_hi = (unsigned short*)(ws + 83886080ULL);
  unsigned short* wqt_lo = (unsigned short*)(ws + 93716480ULL);
  unsigned short* wpt_hi = (unsigned short*)(ws + 103546880ULL);
  unsigned short* wpt_lo = (unsigned short*)(ws + 106823680ULL);
  unsigned int*   ctr    = (unsigned int*)(ws + 83886080ULL);        // dead wqt (8x64B)
  int*            perm   = (int*)(ws + 83886080ULL + 1024);          // dead wqt

  split_hi_kernel<<<5120, 256, 0, stream>>>(x, x_hi, 1310720);
  tsplit_kernel<<<dim3(120, 40), 256, 0, stream>>>(w_qkv, wqt_hi, wqt_lo, 1280, 3840);
  tsplit_kernel<<<dim3(40, 40), 256, 0, stream>>>(w_proj, wpt_hi, wpt_lo, 1280, 1280);
  gemm128_x2<<<dim3(30, 32), 256, 0, stream>>>(x_hi, wqt_hi, wqt_lo, b_qkv,
                                               qf, kf, vf, 4096, 3840, 1280);
  rope_pack_kernel<<<dim3(64, 16), 256, 0, stream>>>(qf, kf, cs, sn, khi, klo);
  vt_pack_kernel<<<dim3(64, 16), 256, 0, stream>>>(vf, vthi, vtlo);
  sched_kernel<<<1, 128, 0, stream>>>(cu, perm, ctr);
  attn_kernel<<<768, 128, 0, stream>>>(qf, khi, klo, vthi, vtlo, cu, o_hi, perm, ctr);
  gemm128_x2<<<dim3(10, 32), 256, 0, stream>>>(o_hi, wpt_hi, wpt_lo, b_proj,
                                               out, nullptr, nullptr, 4096, 1280, 1280);
}